// Round 4
// baseline (8508.907 us; speedup 1.0000x reference)
//
#include <hip/hip_runtime.h>
#include <cstdint>
#include <cstddef>

// Problem constants
#define Bn 16384
#define Dn 768
#define Hn 768
#define G4 3072
#define Tn 10
#define LO_SCALE 4096.0f
#define LO_INV   (1.0f/4096.0f)

typedef _Float16 f16;
typedef _Float16 f16x8 __attribute__((ext_vector_type(8)));
typedef float    f32x4 __attribute__((ext_vector_type(4)));

__device__ __forceinline__ float fexp2(float x) { return __builtin_amdgcn_exp2f(x); }
__device__ __forceinline__ float frcp(float x)  { return __builtin_amdgcn_rcpf(x); }
// fast sigmoid/tanh via v_exp_f32 (~1 ulp) — rel err ~3e-7, routing-safe
__device__ __forceinline__ float fsigm(float x) { return frcp(1.f + fexp2(-1.44269504f * x)); }
__device__ __forceinline__ float ftanh(float x) { return 1.f - 2.f * frcp(1.f + fexp2(2.88539008f * x)); }

__device__ __forceinline__ void gll16(const void* g, void* l) {
    __builtin_amdgcn_global_load_lds((const __attribute__((address_space(1))) void*)g,
                                     (__attribute__((address_space(3))) void*)l, 16, 0, 0);
}

// ---------------------------------------------------------------------------
// Split-fp16 MFMA GEMM, K=768: C[M,N] = A @ Bt^T, A/Bt = hi + lo/4096.
// A staged via global_load_lds (XOR-swizzled); B fragments loaded DIRECTLY
// from global (weights are L2/L3-resident; halves LDS-pipe traffic, which
// R3 counters showed was the bottleneck: 16 ds_read_b128 vs 48 MFMA/iter).
// 128x128 tile, BK=32, 4 waves x 64x64, mfma_f32_16x16x32_f16.
// EPI: 0=f32 out(+bias,relu), 1=split f16 out, 2=f16 out, 3=fused LSTM cell
//      (+ halting-dot atomicAdd into dhalt[row]).
// ---------------------------------------------------------------------------
template <bool SPLIT, int EPI, bool BIAS, bool RELU>
__global__ __launch_bounds__(256) void mgemm(
    const f16* __restrict__ Ah, const f16* __restrict__ Al, int lda,
    const f16* __restrict__ Bh, const f16* __restrict__ Bl,
    float* __restrict__ Cf, f16* __restrict__ Ch, f16* __restrict__ Cl, int ldc,
    const float* __restrict__ bias,
    const float* __restrict__ xwi, float* __restrict__ cst, float* __restrict__ hsum,
    f16* __restrict__ hh_out, f16* __restrict__ hl_out,
    float* __restrict__ dhalt, const float* __restrict__ Whalt,
    long aZ, long bZ, long cZ, long biasZ)
{
    const int z = blockIdx.z;
    if (z) {
        Ah += (long)z * aZ; if (SPLIT) Al += (long)z * aZ;
        Bh += (long)z * bZ; if (SPLIT) Bl += (long)z * bZ;
        if (EPI == 0) Cf += (long)z * cZ;
        if (EPI == 1 || EPI == 2) { Ch += (long)z * cZ; if (EPI == 1) Cl += (long)z * cZ; }
        if (BIAS) bias += (long)z * biasZ;
    }
    __shared__ __align__(16) f16 sA[(SPLIT ? 2 : 1) * 4096];

    const int tid  = threadIdx.x;
    const int w    = tid >> 6, lane = tid & 63;
    const int quad = lane >> 4, l15 = lane & 15;
    const int m0 = blockIdx.x * 128, n0 = blockIdx.y * 128;
    const int wm = (w >> 1) * 64,   wn = (w & 1) * 64;

    // B fragment base: lane reads row (n0+wn+t*16+l15), k-slice quad*8
    const f16* Bbase  = Bh + (long)(n0 + wn + l15) * 768 + quad * 8;
    const f16* Bbasel = SPLIT ? (Bl + (long)(n0 + wn + l15) * 768 + quad * 8) : nullptr;

    f32x4 acc[4][4], accx[4][4];
#pragma unroll
    for (int i = 0; i < 4; i++)
#pragma unroll
        for (int j = 0; j < 4; j++) {
            acc[i][j] = (f32x4){0.f, 0.f, 0.f, 0.f};
            if (SPLIT) accx[i][j] = (f32x4){0.f, 0.f, 0.f, 0.f};
        }

    for (int k0 = 0; k0 < 768; k0 += 32) {
        __syncthreads();
#pragma unroll
        for (int u = 0; u < 2; u++) {
            int s = u * 256 + tid;          // 512 slots x 8 halves
            int r = s >> 2;
            int c = ((s & 3) - (r >> 1)) & 3;   // inverse XOR swizzle
            gll16(Ah + (long)(m0 + r) * lda + k0 + c * 8, &sA[s * 8]);
            if (SPLIT) gll16(Al + (long)(m0 + r) * lda + k0 + c * 8, &sA[4096 + s * 8]);
        }

        // B fragments straight from global (L2-resident weights)
        f16x8 bh[4], bl[4];
#pragma unroll
        for (int t = 0; t < 4; t++) {
            bh[t] = *(const f16x8*)(Bbase + (long)t * 12288 + k0);
            if (SPLIT) bl[t] = *(const f16x8*)(Bbasel + (long)t * 12288 + k0);
        }
        __syncthreads();

        f16x8 ah[4], al[4];
#pragma unroll
        for (int t = 0; t < 4; t++) {
            int ra = wm + t * 16 + l15;
            int ca = (quad + (ra >> 1)) & 3;
            ah[t] = *(const f16x8*)&sA[ra * 32 + ca * 8];
            if (SPLIT) al[t] = *(const f16x8*)&sA[4096 + ra * 32 + ca * 8];
        }
#pragma unroll
        for (int i = 0; i < 4; i++)
#pragma unroll
            for (int j = 0; j < 4; j++) {
                acc[i][j] = __builtin_amdgcn_mfma_f32_16x16x32_f16(ah[i], bh[j], acc[i][j], 0, 0, 0);
                if (SPLIT) {
                    accx[i][j] = __builtin_amdgcn_mfma_f32_16x16x32_f16(ah[i], bl[j], accx[i][j], 0, 0, 0);
                    accx[i][j] = __builtin_amdgcn_mfma_f32_16x16x32_f16(al[i], bh[j], accx[i][j], 0, 0, 0);
                }
            }
    }

    if (EPI == 3) {
        // Fused LSTM pointwise + halting-dot partial. Lane column j fixed.
        const int j = ((n0 + wn) >> 2) + l15;
        const float wj = Whalt[j];
#pragma unroll
        for (int i = 0; i < 4; i++) {
#pragma unroll
            for (int reg = 0; reg < 4; reg++) {
                int r = m0 + wm + i * 16 + quad * 4 + reg;
                long xb = (long)r * G4 + n0 + wn + l15;
                float iv = acc[i][0][reg] + accx[i][0][reg] * LO_INV + xwi[xb];
                float fv = acc[i][1][reg] + accx[i][1][reg] * LO_INV + xwi[xb + 16];
                float gv = acc[i][2][reg] + accx[i][2][reg] * LO_INV + xwi[xb + 32];
                float ov = acc[i][3][reg] + accx[i][3][reg] * LO_INV + xwi[xb + 48];
                long ci = (long)r * Hn + j;
                float cv = fsigm(fv) * cst[ci] + fsigm(iv) * ftanh(gv);
                float hv = fsigm(ov) * ftanh(cv);
                cst[ci] = cv;
                hsum[ci] += hv;
                f16 hh = (f16)hv;
                hh_out[ci] = hh;
                hl_out[ci] = (f16)((hv - (float)hh) * LO_SCALE);
                // halting-dot partial: reduce over the 16 lanes of this quad
                float p = hv * wj;
                p += __shfl_xor(p, 1, 16);
                p += __shfl_xor(p, 2, 16);
                p += __shfl_xor(p, 4, 16);
                p += __shfl_xor(p, 8, 16);
                if (l15 == 0) atomicAdd(&dhalt[r], p);
            }
        }
    } else {
#pragma unroll
        for (int i = 0; i < 4; i++)
#pragma unroll
            for (int j = 0; j < 4; j++) {
                int col = n0 + wn + j * 16 + l15;
                float bv = BIAS ? bias[col] : 0.f;
#pragma unroll
                for (int reg = 0; reg < 4; reg++) {
                    int r = m0 + wm + i * 16 + quad * 4 + reg;
                    float v = acc[i][j][reg] + (SPLIT ? accx[i][j][reg] * LO_INV : 0.f) + bv;
                    if (RELU) v = v > 0.f ? v : 0.f;
                    long o = (long)r * ldc + col;
                    if (EPI == 0) Cf[o] = v;
                    else if (EPI == 2) Ch[o] = (f16)v;
                    else {
                        f16 hh = (f16)v;
                        Ch[o] = hh;
                        Cl[o] = (f16)((v - (float)hh) * LO_SCALE);
                    }
                }
            }
    }
}

// ----------------------------- support kernels -----------------------------

__global__ void split_plain_k(const float* __restrict__ src, f16* __restrict__ dh,
                              f16* __restrict__ dl, long n) {
    long i = (long)blockIdx.x * 256 + threadIdx.x;
    if (i < n) {
        float v = src[i];
        f16 h = (f16)v;
        dh[i] = h;
        dl[i] = (f16)((v - (float)h) * LO_SCALE);
    }
}

// permuted split for Wi/Wh [3072 x 768]: dst row P <- src row g*768 + j,
// j = (P>>6)*16 + (P&15), g = (P>>4)&3.
__global__ void split_perm_k(const float* __restrict__ src, f16* __restrict__ dh,
                             f16* __restrict__ dl) {
    int P = blockIdx.x;
    int q = ((P >> 4) & 3) * Hn + (P >> 6) * 16 + (P & 15);
    const float* s = src + (long)q * 768;
    long o = (long)P * 768;
#pragma unroll
    for (int u = 0; u < 3; u++) {
        int kk = threadIdx.x + u * 256;
        float v = s[kk];
        f16 h = (f16)v;
        dh[o + kk] = h;
        dl[o + kk] = (f16)((v - (float)h) * LO_SCALE);
    }
}

__global__ void bsum_perm_k(const float* __restrict__ bi, const float* __restrict__ bh,
                            float* __restrict__ bsum) {
    int P = blockIdx.x * 256 + threadIdx.x;
    if (P < G4) {
        int q = ((P >> 4) & 3) * Hn + (P >> 6) * 16 + (P & 15);
        bsum[P] = bi[q] + bh[q];
    }
}

// t=0 LSTM step from zero state; xwi is permuted-column layout. Writes raw
// halting dot into d0 (no sigmoid — rem_k applies it).
__global__ __launch_bounds__(256) void lstm0_k(
    const float* __restrict__ xwi, float* __restrict__ cst, float* __restrict__ hsum,
    f16* __restrict__ hh, f16* __restrict__ hl, float* __restrict__ d0,
    const float* __restrict__ Whalt)
{
    const int row = blockIdx.x, tid = threadIdx.x;
    const float* xr = xwi + (long)row * G4;
    const long hb = (long)row * Hn;
    float part = 0.f;
#pragma unroll
    for (int u = 0; u < 3; u++) {
        int j = tid + u * 256;
        int Pb = (j >> 4) * 64 + (j & 15);
        float iv = xr[Pb], gv = xr[Pb + 32], ov = xr[Pb + 48];
        float cv = fsigm(iv) * ftanh(gv);
        float hv = fsigm(ov) * ftanh(cv);
        cst[hb + j] = cv;
        hsum[hb + j] = hv;
        f16 h = (f16)hv;
        hh[hb + j] = h;
        hl[hb + j] = (f16)((hv - (float)h) * LO_SCALE);
        part += hv * Whalt[j];
    }
    __shared__ float red[256];
    red[tid] = part;
    __syncthreads();
    for (int s = 128; s > 0; s >>= 1) {
        if (tid < s) red[tid] += red[tid + s];
        __syncthreads();
    }
    if (tid == 0) d0[row] = red[0];
}

// rem from the 10 per-step halting dots (closed form: rem = sum_t prod_{s<=t}(1-y_s))
__global__ void rem_k(const float* __restrict__ d, const float* __restrict__ bhalt,
                      float* __restrict__ rem, int bc) {
    int r = blockIdx.x * 256 + threadIdx.x;
    if (r >= bc) return;
    float b0 = bhalt[0];
    float prod = 1.f, rm = 0.f;
#pragma unroll
    for (int t = 0; t < Tn; t++) {
        float y = fsigm(d[(long)t * bc + r] + b0);
        prod *= (1.f - y);
        rm += prod;
    }
    rem[r] = rm;
}

// xm = rem*hsum/T, stored as split pair only
__global__ void avgsplit_k(const float* __restrict__ hsum, const float* __restrict__ rem,
                           f16* __restrict__ xmh, f16* __restrict__ xml) {
    long i = (long)blockIdx.x * 256 + threadIdx.x;
    int row = (int)(i / Hn);
    float v = rem[row] * hsum[i] * (1.f / (float)Tn);
    f16 h = (f16)v;
    xmh[i] = h;
    xml[i] = (f16)((v - (float)h) * LO_SCALE);
}

__global__ __launch_bounds__(256) void moe_gate_k(
    const f16* __restrict__ xmh, const f16* __restrict__ xml,
    const float* __restrict__ gW, const float* __restrict__ gb,
    float* __restrict__ wout, int* __restrict__ idxout)
{
    const int row = blockIdx.x, tid = threadIdx.x;
    const long xb = (long)row * Hn;
    float p[4] = {0.f, 0.f, 0.f, 0.f};
#pragma unroll
    for (int u = 0; u < 3; u++) {
        int j = tid + u * 256;
        float xv = (float)xmh[xb + j] + (float)xml[xb + j] * LO_INV;
        p[0] += xv * gW[j];
        p[1] += xv * gW[Hn + j];
        p[2] += xv * gW[2 * Hn + j];
        p[3] += xv * gW[3 * Hn + j];
    }
    __shared__ float red[256];
    __shared__ float logit[4];
    for (int e = 0; e < 4; e++) {
        red[tid] = p[e];
        __syncthreads();
        for (int s = 128; s > 0; s >>= 1) {
            if (tid < s) red[tid] += red[tid + s];
            __syncthreads();
        }
        if (tid == 0) logit[e] = red[0] + gb[e];
        __syncthreads();
    }
    if (tid == 0) {
        int i0 = 0;
        for (int e = 1; e < 4; e++) if (logit[e] > logit[i0]) i0 = e;
        int i1 = -1;
        for (int e = 0; e < 4; e++) {
            if (e == i0) continue;
            if (i1 < 0 || logit[e] > logit[i1]) i1 = e;
        }
        float ex = expf(logit[i1] - logit[i0]);
        wout[2 * row] = 1.f / (1.f + ex);
        wout[2 * row + 1] = ex / (1.f + ex);
        idxout[2 * row] = i0;
        idxout[2 * row + 1] = i1;
    }
}

// SO=1: write split pair (level-0 -> next xm). SO=0: write f32 (pre-LN).
template <bool SO>
__global__ void combine_k(const float* __restrict__ eo, const float* __restrict__ wv,
                          const int* __restrict__ idx, float* __restrict__ dst,
                          f16* __restrict__ dh, f16* __restrict__ dl) {
    long i = (long)blockIdx.x * 256 + threadIdx.x;
    int row = (int)(i / Hn);
    int d = (int)(i - (long)row * Hn);
    long base = (long)row * G4;
    float v = wv[2 * row]     * eo[base + (long)idx[2 * row]     * Hn + d]
            + wv[2 * row + 1] * eo[base + (long)idx[2 * row + 1] * Hn + d];
    if (SO) {
        f16 h = (f16)v;
        dh[i] = h;
        dl[i] = (f16)((v - (float)h) * LO_SCALE);
    } else {
        dst[i] = v;
    }
}

__global__ __launch_bounds__(256) void layernorm_k(
    const float* __restrict__ in, const float* __restrict__ gamma,
    const float* __restrict__ beta, float* __restrict__ out)
{
    const int row = blockIdx.x, tid = threadIdx.x;
    const float* xr = in + (long)row * Dn;
    float v[3], s = 0.f, s2 = 0.f;
#pragma unroll
    for (int u = 0; u < 3; u++) {
        v[u] = xr[tid + u * 256];
        s += v[u];
        s2 += v[u] * v[u];
    }
    __shared__ float r1[256], r2[256];
    __shared__ float smu, srs;
    r1[tid] = s; r2[tid] = s2;
    __syncthreads();
    for (int st = 128; st > 0; st >>= 1) {
        if (tid < st) { r1[tid] += r1[tid + st]; r2[tid] += r2[tid + st]; }
        __syncthreads();
    }
    if (tid == 0) {
        float mu = r1[0] * (1.f / (float)Dn);
        float var = r2[0] * (1.f / (float)Dn) - mu * mu;
        smu = mu;
        srs = 1.f / sqrtf(var + 1e-5f);
    }
    __syncthreads();
    float mu = smu, rs = srs;
#pragma unroll
    for (int u = 0; u < 3; u++) {
        int j = tid + u * 256;
        out[(long)row * Dn + j] = (v[u] - mu) * rs * gamma[j] + beta[j];
    }
}

// ---------------------------------------------------------------------------

extern "C" void kernel_launch(void* const* d_in, const int* in_sizes, int n_in,
                              void* d_out, int out_size, void* d_ws, size_t ws_size,
                              hipStream_t stream) {
    (void)in_sizes; (void)n_in; (void)out_size;
    const float* x     = (const float*)d_in[0];
    const float* Wi    = (const float*)d_in[1];
    const float* Wh    = (const float*)d_in[2];
    const float* bi    = (const float*)d_in[3];
    const float* bh    = (const float*)d_in[4];
    const float* Whalt = (const float*)d_in[5];
    const float* bhalt = (const float*)d_in[6];
    const float* gateW = (const float*)d_in[7];
    const float* gateb = (const float*)d_in[8];
    const float* W1    = (const float*)d_in[9];
    const float* b1    = (const float*)d_in[10];
    const float* W2    = (const float*)d_in[11];
    const float* b2    = (const float*)d_in[12];
    const float* gamma = (const float*)d_in[13];
    const float* beta  = (const float*)d_in[14];
    float* out = (float*)d_out;

    char* p = (char*)d_ws;
    auto carve = [&](size_t bytes) { char* r = p; p += (bytes + 255) & ~(size_t)255; return r; };

    const long WIHN = (long)G4 * 768;
    const long WEHN = (long)8 * 768 * 768;
    f16* Wih = (f16*)carve(WIHN * 2); f16* Wil = (f16*)carve(WIHN * 2);
    f16* Whh = (f16*)carve(WIHN * 2); f16* Whl = (f16*)carve(WIHN * 2);
    f16* W1h = (f16*)carve(WEHN * 2); f16* W1l = (f16*)carve(WEHN * 2);
    f16* W2h = (f16*)carve(WEHN * 2); f16* W2l = (f16*)carve(WEHN * 2);
    float* bsum = (float*)carve(G4 * 4);
    size_t fixed = (size_t)(p - (char*)d_ws);

    // per-row bytes: xwi 12288 + cst 3072 + hsum 3072 + pool 15360 + d 40
    //              + rem 4 + wbuf 8 + ibuf 8 ~= 33852 (+pads)
    int Bc = Bn;
    while (Bc > 128) {
        size_t need = fixed + (size_t)Bc * 34100 + 64 * 256;
        if (need <= ws_size) break;
        Bc >>= 1;
    }
    const int nChunks = Bn / Bc;

    float* xwi   = (float*)carve((size_t)Bc * G4 * 4);   // reused as eo in MoE
    float* cst   = (float*)carve((size_t)Bc * 768 * 4);
    float* hsumb = (float*)carve((size_t)Bc * 768 * 4);  // reused as pre-LN dst
    char*  pool  = carve((size_t)Bc * 15360);
    float* d     = (float*)carve((size_t)Bc * Tn * 4);
    float* rem   = (float*)carve((size_t)Bc * 4);
    float* wbuf  = (float*)carve((size_t)Bc * 2 * 4);
    int*   ibuf  = (int*)carve((size_t)Bc * 2 * 4);

    // pool aliases — LSTM phase
    f16* xh  = (f16*)pool;
    f16* xl  = xh + (size_t)Bc * 768;
    f16* h0h = xl + (size_t)Bc * 768;
    f16* h0l = h0h + (size_t)Bc * 768;
    f16* h1h = h0l + (size_t)Bc * 768;
    f16* h1l = h1h + (size_t)Bc * 768;
    // pool aliases — MoE phase (LSTM buffers dead by then)
    f16* xmh = (f16*)pool;
    f16* xml = xmh + (size_t)Bc * 768;
    f16* hmh = xml + (size_t)Bc * 768;
    f16* hml = hmh + (size_t)Bc * G4;

    // weight prep (once per call)
    split_perm_k<<<G4, 256, 0, stream>>>(Wi, Wih, Wil);
    split_perm_k<<<G4, 256, 0, stream>>>(Wh, Whh, Whl);
    split_plain_k<<<(int)((WEHN + 255) / 256), 256, 0, stream>>>(W1, W1h, W1l, WEHN);
    split_plain_k<<<(int)((WEHN + 255) / 256), 256, 0, stream>>>(W2, W2h, W2l, WEHN);
    bsum_perm_k<<<G4 / 256, 256, 0, stream>>>(bi, bh, bsum);

    dim3 blk(256);
    dim3 g24(Bc / 128, 24, 1);
    dim3 g6z(Bc / 128, 6, 4);
    const int ew = Bc * 3;
    const long EXP_OFF = (long)4 * 768 * 768;

    for (int ch = 0; ch < nChunks; ch++) {
        const float* xc = x + (size_t)ch * Bc * Dn;
        float* outc = out + (size_t)ch * Bc * Dn;

        split_plain_k<<<ew, blk, 0, stream>>>(xc, xh, xl, (long)Bc * 768);

        // xwi = x @ Wi^T + (bi+bh)   (permuted columns)
        mgemm<true, 0, true, false><<<g24, blk, 0, stream>>>(
            xh, xl, 768, Wih, Wil, xwi, nullptr, nullptr, G4, bsum,
            nullptr, nullptr, nullptr, nullptr, nullptr, nullptr, nullptr, 0, 0, 0, 0);

        hipMemsetAsync(d, 0, (size_t)Bc * Tn * 4, stream);
        lstm0_k<<<Bc, blk, 0, stream>>>(xwi, cst, hsumb, h0h, h0l, d, Whalt);

        for (int t = 1; t < Tn; t++) {
            f16* rah = (t & 1) ? h0h : h1h;
            f16* ral = (t & 1) ? h0l : h1l;
            f16* wah = (t & 1) ? h1h : h0h;
            f16* wal = (t & 1) ? h1l : h0l;
            mgemm<true, 3, false, false><<<g24, blk, 0, stream>>>(
                rah, ral, 768, Whh, Whl, nullptr, nullptr, nullptr, 0, nullptr,
                xwi, cst, hsumb, wah, wal, d + (size_t)t * Bc, Whalt, 0, 0, 0, 0);
        }

        rem_k<<<(Bc + 255) / 256, blk, 0, stream>>>(d, bhalt, rem, Bc);
        avgsplit_k<<<ew, blk, 0, stream>>>(hsumb, rem, xmh, xml);

        float* eo = xwi;  // reuse
        for (int l = 0; l < 2; l++) {
            moe_gate_k<<<Bc, blk, 0, stream>>>(xmh, xml, gateW + (long)l * G4,
                                               gateb + l * 4, wbuf, ibuf);
            if (l == 0) {
                mgemm<true, 1, true, true><<<g24, blk, 0, stream>>>(
                    xmh, xml, 768, W1h, W1l, nullptr, hmh, hml, G4, b1,
                    nullptr, nullptr, nullptr, nullptr, nullptr, nullptr, nullptr, 0, 0, 0, 0);
                mgemm<true, 0, true, false><<<g6z, blk, 0, stream>>>(
                    hmh, hml, G4, W2h, W2l, eo, nullptr, nullptr, G4, b2,
                    nullptr, nullptr, nullptr, nullptr, nullptr, nullptr, nullptr,
                    768, (long)768 * 768, 768, 768);
                combine_k<true><<<ew, blk, 0, stream>>>(eo, wbuf, ibuf, nullptr, xmh, xml);
            } else {
                mgemm<false, 2, true, true><<<g24, blk, 0, stream>>>(
                    xmh, nullptr, 768, W1h + EXP_OFF, nullptr, nullptr, hmh, nullptr, G4,
                    b1 + G4, nullptr, nullptr, nullptr, nullptr, nullptr, nullptr, nullptr,
                    0, 0, 0, 0);
                mgemm<false, 0, true, false><<<g6z, blk, 0, stream>>>(
                    hmh, nullptr, G4, W2h + EXP_OFF, nullptr, eo, nullptr, nullptr, G4,
                    b2 + G4, nullptr, nullptr, nullptr, nullptr, nullptr, nullptr, nullptr,
                    768, (long)768 * 768, 768, 768);
                combine_k<false><<<ew, blk, 0, stream>>>(eo, wbuf, ibuf, hsumb, nullptr, nullptr);
            }
        }

        layernorm_k<<<Bc, blk, 0, stream>>>(hsumb, gamma, beta, outc);
    }
}

// Round 5
// 6522.244 us; speedup vs baseline: 1.3046x; 1.3046x over previous
//
#include <hip/hip_runtime.h>
#include <cstdint>
#include <cstddef>

// Problem constants
#define Bn 16384
#define Dn 768
#define Hn 768
#define G4 3072
#define Tn 10
#define LO_SCALE 4096.0f
#define LO_INV   (1.0f/4096.0f)

typedef _Float16 f16;
typedef _Float16 f16x8 __attribute__((ext_vector_type(8)));
typedef float    f32x4 __attribute__((ext_vector_type(4)));

__device__ __forceinline__ float fexp2(float x) { return __builtin_amdgcn_exp2f(x); }
__device__ __forceinline__ float frcp(float x)  { return __builtin_amdgcn_rcpf(x); }
__device__ __forceinline__ float fsigm(float x) { return frcp(1.f + fexp2(-1.44269504f * x)); }
__device__ __forceinline__ float ftanh(float x) { return 1.f - 2.f * frcp(1.f + fexp2(2.88539008f * x)); }

__device__ __forceinline__ void gll16(const void* g, void* l) {
    __builtin_amdgcn_global_load_lds((const __attribute__((address_space(1))) void*)g,
                                     (__attribute__((address_space(3))) void*)l, 16, 0, 0);
}

// ---------------------------------------------------------------------------
// Split-fp16 MFMA GEMM, K=768: C[M,N] = A @ Bt^T, A/Bt = hi + lo/4096.
// Double-buffered LDS, ONE barrier per K-iter: the vmcnt(0) the compiler
// emits before s_barrier waits on loads issued a FULL iteration earlier
// (latency hidden by iter-1's ds_read+MFMA). Stage of buf^1 is issued right
// after the barrier (its previous readers all retired before the barrier).
// 128x128 tile, BK=32, 4 waves x 64x64, mfma_f32_16x16x32_f16, XOR-swizzled
// LDS (0 bank conflicts, verified R3).
// Grid: blockIdx.x = N-tile (fast -> consecutive blocks share the A tile in
// L2), blockIdx.y = M-tile, blockIdx.z = expert group.
// EPI: 0=f32 out(+bias,relu), 1=split f16 out, 2=f16 out, 3=fused LSTM cell
//      (+ halting-dot atomicAdd into dhalt[row]).
// ---------------------------------------------------------------------------
template <bool SPLIT, int EPI, bool BIAS, bool RELU>
__global__ __launch_bounds__(256) void mgemm(
    const f16* __restrict__ Ah, const f16* __restrict__ Al, int lda,
    const f16* __restrict__ Bh, const f16* __restrict__ Bl,
    float* __restrict__ Cf, f16* __restrict__ Ch, f16* __restrict__ Cl, int ldc,
    const float* __restrict__ bias,
    const float* __restrict__ xwi, float* __restrict__ cst, float* __restrict__ hsum,
    f16* __restrict__ hh_out, f16* __restrict__ hl_out,
    float* __restrict__ dhalt, const float* __restrict__ Whalt,
    long aZ, long bZ, long cZ, long biasZ)
{
    const int z = blockIdx.z;
    if (z) {
        Ah += (long)z * aZ; if (SPLIT) Al += (long)z * aZ;
        Bh += (long)z * bZ; if (SPLIT) Bl += (long)z * bZ;
        if (EPI == 0) Cf += (long)z * cZ;
        if (EPI == 1 || EPI == 2) { Ch += (long)z * cZ; if (EPI == 1) Cl += (long)z * cZ; }
        if (BIAS) bias += (long)z * biasZ;
    }
    constexpr int HALF = SPLIT ? 2 : 1;
    __shared__ __align__(16) f16 sA[2][HALF * 4096];
    __shared__ __align__(16) f16 sB[2][HALF * 4096];

    const int tid  = threadIdx.x;
    const int w    = tid >> 6, lane = tid & 63;
    const int quad = lane >> 4, l15 = lane & 15;
    const int n0 = blockIdx.x * 128, m0 = blockIdx.y * 128;
    const int wm = (w >> 1) * 64,   wn = (w & 1) * 64;

    // staging slot for this thread (XOR-swizzled within a row's 4 x 16B groups)
    const int sr0 = tid >> 2;                         // rows 0..63  (u=0)
    const int sc0 = (((tid & 3) - (sr0 >> 1)) & 3);
    const int sr1 = (tid + 256) >> 2;                 // rows 64..127 (u=1)
    const int sc1 = (((tid & 3) - (sr1 >> 1)) & 3);

    auto stage = [&](int sel, int k0) {
        gll16(Ah + (long)(m0 + sr0) * lda + k0 + sc0 * 8, &sA[sel][tid * 8]);
        gll16(Bh + (long)(n0 + sr0) * 768 + k0 + sc0 * 8, &sB[sel][tid * 8]);
        gll16(Ah + (long)(m0 + sr1) * lda + k0 + sc1 * 8, &sA[sel][(tid + 256) * 8]);
        gll16(Bh + (long)(n0 + sr1) * 768 + k0 + sc1 * 8, &sB[sel][(tid + 256) * 8]);
        if (SPLIT) {
            gll16(Al + (long)(m0 + sr0) * lda + k0 + sc0 * 8, &sA[sel][4096 + tid * 8]);
            gll16(Bl + (long)(n0 + sr0) * 768 + k0 + sc0 * 8, &sB[sel][4096 + tid * 8]);
            gll16(Al + (long)(m0 + sr1) * lda + k0 + sc1 * 8, &sA[sel][4096 + (tid + 256) * 8]);
            gll16(Bl + (long)(n0 + sr1) * 768 + k0 + sc1 * 8, &sB[sel][4096 + (tid + 256) * 8]);
        }
    };

    f32x4 acc[4][4], accx[4][4];
#pragma unroll
    for (int i = 0; i < 4; i++)
#pragma unroll
        for (int j = 0; j < 4; j++) {
            acc[i][j] = (f32x4){0.f, 0.f, 0.f, 0.f};
            if (SPLIT) accx[i][j] = (f32x4){0.f, 0.f, 0.f, 0.f};
        }

    stage(0, 0);
    for (int it = 0; it < 24; it++) {
        __syncthreads();                    // implied vmcnt(0): waits iter-old stage
        if (it + 1 < 24) stage((it + 1) & 1, (it + 1) * 32);
        const int sel = it & 1;

        f16x8 ah[4], al[4], bh[4], bl[4];
#pragma unroll
        for (int t = 0; t < 4; t++) {
            int ra = wm + t * 16 + l15;
            int ca = (quad + (ra >> 1)) & 3;
            ah[t] = *(const f16x8*)&sA[sel][ra * 32 + ca * 8];
            if (SPLIT) al[t] = *(const f16x8*)&sA[sel][4096 + ra * 32 + ca * 8];
            int rb = wn + t * 16 + l15;
            int cb = (quad + (rb >> 1)) & 3;
            bh[t] = *(const f16x8*)&sB[sel][rb * 32 + cb * 8];
            if (SPLIT) bl[t] = *(const f16x8*)&sB[sel][4096 + rb * 32 + cb * 8];
        }
#pragma unroll
        for (int i = 0; i < 4; i++)
#pragma unroll
            for (int j = 0; j < 4; j++) {
                acc[i][j] = __builtin_amdgcn_mfma_f32_16x16x32_f16(ah[i], bh[j], acc[i][j], 0, 0, 0);
                if (SPLIT) {
                    accx[i][j] = __builtin_amdgcn_mfma_f32_16x16x32_f16(ah[i], bl[j], accx[i][j], 0, 0, 0);
                    accx[i][j] = __builtin_amdgcn_mfma_f32_16x16x32_f16(al[i], bh[j], accx[i][j], 0, 0, 0);
                }
            }
    }

    if (EPI == 3) {
        const int j = ((n0 + wn) >> 2) + l15;
        const float wj = Whalt[j];
#pragma unroll
        for (int i = 0; i < 4; i++) {
#pragma unroll
            for (int reg = 0; reg < 4; reg++) {
                int r = m0 + wm + i * 16 + quad * 4 + reg;
                long xb = (long)r * G4 + n0 + wn + l15;
                float iv = acc[i][0][reg] + accx[i][0][reg] * LO_INV + xwi[xb];
                float fv = acc[i][1][reg] + accx[i][1][reg] * LO_INV + xwi[xb + 16];
                float gv = acc[i][2][reg] + accx[i][2][reg] * LO_INV + xwi[xb + 32];
                float ov = acc[i][3][reg] + accx[i][3][reg] * LO_INV + xwi[xb + 48];
                long ci = (long)r * Hn + j;
                float cv = fsigm(fv) * cst[ci] + fsigm(iv) * ftanh(gv);
                float hv = fsigm(ov) * ftanh(cv);
                cst[ci] = cv;
                hsum[ci] += hv;
                f16 hh = (f16)hv;
                hh_out[ci] = hh;
                hl_out[ci] = (f16)((hv - (float)hh) * LO_SCALE);
                float p = hv * wj;
                p += __shfl_xor(p, 1, 16);
                p += __shfl_xor(p, 2, 16);
                p += __shfl_xor(p, 4, 16);
                p += __shfl_xor(p, 8, 16);
                if (l15 == 0) atomicAdd(&dhalt[r], p);
            }
        }
    } else {
#pragma unroll
        for (int i = 0; i < 4; i++)
#pragma unroll
            for (int j = 0; j < 4; j++) {
                int col = n0 + wn + j * 16 + l15;
                float bv = BIAS ? bias[col] : 0.f;
#pragma unroll
                for (int reg = 0; reg < 4; reg++) {
                    int r = m0 + wm + i * 16 + quad * 4 + reg;
                    float v = acc[i][j][reg] + (SPLIT ? accx[i][j][reg] * LO_INV : 0.f) + bv;
                    if (RELU) v = v > 0.f ? v : 0.f;
                    long o = (long)r * ldc + col;
                    if (EPI == 0) Cf[o] = v;
                    else if (EPI == 2) Ch[o] = (f16)v;
                    else {
                        f16 hh = (f16)v;
                        Ch[o] = hh;
                        Cl[o] = (f16)((v - (float)hh) * LO_SCALE);
                    }
                }
            }
    }
}

// ----------------------------- support kernels -----------------------------

__global__ void split_plain_k(const float* __restrict__ src, f16* __restrict__ dh,
                              f16* __restrict__ dl, long n) {
    long i = (long)blockIdx.x * 256 + threadIdx.x;
    if (i < n) {
        float v = src[i];
        f16 h = (f16)v;
        dh[i] = h;
        dl[i] = (f16)((v - (float)h) * LO_SCALE);
    }
}

// permuted split for Wi/Wh [3072 x 768]: dst row P <- src row g*768 + j,
// j = (P>>6)*16 + (P&15), g = (P>>4)&3.
__global__ void split_perm_k(const float* __restrict__ src, f16* __restrict__ dh,
                             f16* __restrict__ dl) {
    int P = blockIdx.x;
    int q = ((P >> 4) & 3) * Hn + (P >> 6) * 16 + (P & 15);
    const float* s = src + (long)q * 768;
    long o = (long)P * 768;
#pragma unroll
    for (int u = 0; u < 3; u++) {
        int kk = threadIdx.x + u * 256;
        float v = s[kk];
        f16 h = (f16)v;
        dh[o + kk] = h;
        dl[o + kk] = (f16)((v - (float)h) * LO_SCALE);
    }
}

__global__ void bsum_perm_k(const float* __restrict__ bi, const float* __restrict__ bh,
                            float* __restrict__ bsum) {
    int P = blockIdx.x * 256 + threadIdx.x;
    if (P < G4) {
        int q = ((P >> 4) & 3) * Hn + (P >> 6) * 16 + (P & 15);
        bsum[P] = bi[q] + bh[q];
    }
}

// t=0 LSTM step from zero state; xwi is permuted-column layout. Raw halting
// dot -> d0 (rem_k applies sigmoid).
__global__ __launch_bounds__(256) void lstm0_k(
    const float* __restrict__ xwi, float* __restrict__ cst, float* __restrict__ hsum,
    f16* __restrict__ hh, f16* __restrict__ hl, float* __restrict__ d0,
    const float* __restrict__ Whalt)
{
    const int row = blockIdx.x, tid = threadIdx.x;
    const float* xr = xwi + (long)row * G4;
    const long hb = (long)row * Hn;
    float part = 0.f;
#pragma unroll
    for (int u = 0; u < 3; u++) {
        int j = tid + u * 256;
        int Pb = (j >> 4) * 64 + (j & 15);
        float iv = xr[Pb], gv = xr[Pb + 32], ov = xr[Pb + 48];
        float cv = fsigm(iv) * ftanh(gv);
        float hv = fsigm(ov) * ftanh(cv);
        cst[hb + j] = cv;
        hsum[hb + j] = hv;
        f16 h = (f16)hv;
        hh[hb + j] = h;
        hl[hb + j] = (f16)((hv - (float)h) * LO_SCALE);
        part += hv * Whalt[j];
    }
    __shared__ float red[256];
    red[tid] = part;
    __syncthreads();
    for (int s = 128; s > 0; s >>= 1) {
        if (tid < s) red[tid] += red[tid + s];
        __syncthreads();
    }
    if (tid == 0) d0[row] = red[0];
}

// rem from the 10 per-step halting dots: rem = sum_t prod_{s<=t}(1-y_s)
__global__ void rem_k(const float* __restrict__ d, const float* __restrict__ bhalt,
                      float* __restrict__ rem, int bc) {
    int r = blockIdx.x * 256 + threadIdx.x;
    if (r >= bc) return;
    float b0 = bhalt[0];
    float prod = 1.f, rm = 0.f;
#pragma unroll
    for (int t = 0; t < Tn; t++) {
        float y = fsigm(d[(long)t * bc + r] + b0);
        prod *= (1.f - y);
        rm += prod;
    }
    rem[r] = rm;
}

__global__ void avgsplit_k(const float* __restrict__ hsum, const float* __restrict__ rem,
                           f16* __restrict__ xmh, f16* __restrict__ xml) {
    long i = (long)blockIdx.x * 256 + threadIdx.x;
    int row = (int)(i / Hn);
    float v = rem[row] * hsum[i] * (1.f / (float)Tn);
    f16 h = (f16)v;
    xmh[i] = h;
    xml[i] = (f16)((v - (float)h) * LO_SCALE);
}

__global__ __launch_bounds__(256) void moe_gate_k(
    const f16* __restrict__ xmh, const f16* __restrict__ xml,
    const float* __restrict__ gW, const float* __restrict__ gb,
    float* __restrict__ wout, int* __restrict__ idxout)
{
    const int row = blockIdx.x, tid = threadIdx.x;
    const long xb = (long)row * Hn;
    float p[4] = {0.f, 0.f, 0.f, 0.f};
#pragma unroll
    for (int u = 0; u < 3; u++) {
        int j = tid + u * 256;
        float xv = (float)xmh[xb + j] + (float)xml[xb + j] * LO_INV;
        p[0] += xv * gW[j];
        p[1] += xv * gW[Hn + j];
        p[2] += xv * gW[2 * Hn + j];
        p[3] += xv * gW[3 * Hn + j];
    }
    __shared__ float red[256];
    __shared__ float logit[4];
    for (int e = 0; e < 4; e++) {
        red[tid] = p[e];
        __syncthreads();
        for (int s = 128; s > 0; s >>= 1) {
            if (tid < s) red[tid] += red[tid + s];
            __syncthreads();
        }
        if (tid == 0) logit[e] = red[0] + gb[e];
        __syncthreads();
    }
    if (tid == 0) {
        int i0 = 0;
        for (int e = 1; e < 4; e++) if (logit[e] > logit[i0]) i0 = e;
        int i1 = -1;
        for (int e = 0; e < 4; e++) {
            if (e == i0) continue;
            if (i1 < 0 || logit[e] > logit[i1]) i1 = e;
        }
        float ex = expf(logit[i1] - logit[i0]);
        wout[2 * row] = 1.f / (1.f + ex);
        wout[2 * row + 1] = ex / (1.f + ex);
        idxout[2 * row] = i0;
        idxout[2 * row + 1] = i1;
    }
}

template <bool SO>
__global__ void combine_k(const float* __restrict__ eo, const float* __restrict__ wv,
                          const int* __restrict__ idx, float* __restrict__ dst,
                          f16* __restrict__ dh, f16* __restrict__ dl) {
    long i = (long)blockIdx.x * 256 + threadIdx.x;
    int row = (int)(i / Hn);
    int d = (int)(i - (long)row * Hn);
    long base = (long)row * G4;
    float v = wv[2 * row]     * eo[base + (long)idx[2 * row]     * Hn + d]
            + wv[2 * row + 1] * eo[base + (long)idx[2 * row + 1] * Hn + d];
    if (SO) {
        f16 h = (f16)v;
        dh[i] = h;
        dl[i] = (f16)((v - (float)h) * LO_SCALE);
    } else {
        dst[i] = v;
    }
}

__global__ __launch_bounds__(256) void layernorm_k(
    const float* __restrict__ in, const float* __restrict__ gamma,
    const float* __restrict__ beta, float* __restrict__ out)
{
    const int row = blockIdx.x, tid = threadIdx.x;
    const float* xr = in + (long)row * Dn;
    float v[3], s = 0.f, s2 = 0.f;
#pragma unroll
    for (int u = 0; u < 3; u++) {
        v[u] = xr[tid + u * 256];
        s += v[u];
        s2 += v[u] * v[u];
    }
    __shared__ float r1[256], r2[256];
    __shared__ float smu, srs;
    r1[tid] = s; r2[tid] = s2;
    __syncthreads();
    for (int st = 128; st > 0; st >>= 1) {
        if (tid < st) { r1[tid] += r1[tid + st]; r2[tid] += r2[tid + st]; }
        __syncthreads();
    }
    if (tid == 0) {
        float mu = r1[0] * (1.f / (float)Dn);
        float var = r2[0] * (1.f / (float)Dn) - mu * mu;
        smu = mu;
        srs = 1.f / sqrtf(var + 1e-5f);
    }
    __syncthreads();
    float mu = smu, rs = srs;
#pragma unroll
    for (int u = 0; u < 3; u++) {
        int j = tid + u * 256;
        out[(long)row * Dn + j] = (v[u] - mu) * rs * gamma[j] + beta[j];
    }
}

// ---------------------------------------------------------------------------

extern "C" void kernel_launch(void* const* d_in, const int* in_sizes, int n_in,
                              void* d_out, int out_size, void* d_ws, size_t ws_size,
                              hipStream_t stream) {
    (void)in_sizes; (void)n_in; (void)out_size;
    const float* x     = (const float*)d_in[0];
    const float* Wi    = (const float*)d_in[1];
    const float* Wh    = (const float*)d_in[2];
    const float* bi    = (const float*)d_in[3];
    const float* bh    = (const float*)d_in[4];
    const float* Whalt = (const float*)d_in[5];
    const float* bhalt = (const float*)d_in[6];
    const float* gateW = (const float*)d_in[7];
    const float* gateb = (const float*)d_in[8];
    const float* W1    = (const float*)d_in[9];
    const float* b1    = (const float*)d_in[10];
    const float* W2    = (const float*)d_in[11];
    const float* b2    = (const float*)d_in[12];
    const float* gamma = (const float*)d_in[13];
    const float* beta  = (const float*)d_in[14];
    float* out = (float*)d_out;

    char* p = (char*)d_ws;
    auto carve = [&](size_t bytes) { char* r = p; p += (bytes + 255) & ~(size_t)255; return r; };

    const long WIHN = (long)G4 * 768;
    const long WEHN = (long)8 * 768 * 768;
    f16* Wih = (f16*)carve(WIHN * 2); f16* Wil = (f16*)carve(WIHN * 2);
    f16* Whh = (f16*)carve(WIHN * 2); f16* Whl = (f16*)carve(WIHN * 2);
    f16* W1h = (f16*)carve(WEHN * 2); f16* W1l = (f16*)carve(WEHN * 2);
    f16* W2h = (f16*)carve(WEHN * 2); f16* W2l = (f16*)carve(WEHN * 2);
    float* bsum = (float*)carve(G4 * 4);
    size_t fixed = (size_t)(p - (char*)d_ws);

    int Bc = Bn;
    while (Bc > 128) {
        size_t need = fixed + (size_t)Bc * 34100 + 64 * 256;
        if (need <= ws_size) break;
        Bc >>= 1;
    }
    const int nChunks = Bn / Bc;

    float* xwi   = (float*)carve((size_t)Bc * G4 * 4);   // reused as eo in MoE
    float* cst   = (float*)carve((size_t)Bc * 768 * 4);
    float* hsumb = (float*)carve((size_t)Bc * 768 * 4);  // reused as pre-LN dst
    char*  pool  = carve((size_t)Bc * 15360);
    float* d     = (float*)carve((size_t)Bc * Tn * 4);
    float* rem   = (float*)carve((size_t)Bc * 4);
    float* wbuf  = (float*)carve((size_t)Bc * 2 * 4);
    int*   ibuf  = (int*)carve((size_t)Bc * 2 * 4);

    // pool aliases — LSTM phase
    f16* xh  = (f16*)pool;
    f16* xl  = xh + (size_t)Bc * 768;
    f16* h0h = xl + (size_t)Bc * 768;
    f16* h0l = h0h + (size_t)Bc * 768;
    f16* h1h = h0l + (size_t)Bc * 768;
    f16* h1l = h1h + (size_t)Bc * 768;
    // pool aliases — MoE phase
    f16* xmh = (f16*)pool;
    f16* xml = xmh + (size_t)Bc * 768;
    f16* hmh = xml + (size_t)Bc * 768;
    f16* hml = hmh + (size_t)Bc * G4;

    split_perm_k<<<G4, 256, 0, stream>>>(Wi, Wih, Wil);
    split_perm_k<<<G4, 256, 0, stream>>>(Wh, Whh, Whl);
    split_plain_k<<<(int)((WEHN + 255) / 256), 256, 0, stream>>>(W1, W1h, W1l, WEHN);
    split_plain_k<<<(int)((WEHN + 255) / 256), 256, 0, stream>>>(W2, W2h, W2l, WEHN);
    bsum_perm_k<<<G4 / 256, 256, 0, stream>>>(bi, bh, bsum);

    dim3 blk(256);
    dim3 g24(24, Bc / 128, 1);   // x = N-tile (fast), y = M-tile
    dim3 g6z(6, Bc / 128, 4);
    const int ew = Bc * 3;
    const long EXP_OFF = (long)4 * 768 * 768;

    for (int ch = 0; ch < nChunks; ch++) {
        const float* xc = x + (size_t)ch * Bc * Dn;
        float* outc = out + (size_t)ch * Bc * Dn;

        split_plain_k<<<ew, blk, 0, stream>>>(xc, xh, xl, (long)Bc * 768);

        // xwi = x @ Wi^T + (bi+bh)   (permuted columns)
        mgemm<true, 0, true, false><<<g24, blk, 0, stream>>>(
            xh, xl, 768, Wih, Wil, xwi, nullptr, nullptr, G4, bsum,
            nullptr, nullptr, nullptr, nullptr, nullptr, nullptr, nullptr, 0, 0, 0, 0);

        hipMemsetAsync(d, 0, (size_t)Bc * Tn * 4, stream);
        lstm0_k<<<Bc, blk, 0, stream>>>(xwi, cst, hsumb, h0h, h0l, d, Whalt);

        for (int t = 1; t < Tn; t++) {
            f16* rah = (t & 1) ? h0h : h1h;
            f16* ral = (t & 1) ? h0l : h1l;
            f16* wah = (t & 1) ? h1h : h0h;
            f16* wal = (t & 1) ? h1l : h0l;
            mgemm<true, 3, false, false><<<g24, blk, 0, stream>>>(
                rah, ral, 768, Whh, Whl, nullptr, nullptr, nullptr, 0, nullptr,
                xwi, cst, hsumb, wah, wal, d + (size_t)t * Bc, Whalt, 0, 0, 0, 0);
        }

        rem_k<<<(Bc + 255) / 256, blk, 0, stream>>>(d, bhalt, rem, Bc);
        avgsplit_k<<<ew, blk, 0, stream>>>(hsumb, rem, xmh, xml);

        float* eo = xwi;  // reuse
        for (int l = 0; l < 2; l++) {
            moe_gate_k<<<Bc, blk, 0, stream>>>(xmh, xml, gateW + (long)l * G4,
                                               gateb + l * 4, wbuf, ibuf);
            if (l == 0) {
                mgemm<true, 1, true, true><<<g24, blk, 0, stream>>>(
                    xmh, xml, 768, W1h, W1l, nullptr, hmh, hml, G4, b1,
                    nullptr, nullptr, nullptr, nullptr, nullptr, nullptr, nullptr, 0, 0, 0, 0);
                mgemm<true, 0, true, false><<<g6z, blk, 0, stream>>>(
                    hmh, hml, G4, W2h, W2l, eo, nullptr, nullptr, G4, b2,
                    nullptr, nullptr, nullptr, nullptr, nullptr, nullptr, nullptr,
                    768, (long)768 * 768, 768, 768);
                combine_k<true><<<ew, blk, 0, stream>>>(eo, wbuf, ibuf, nullptr, xmh, xml);
            } else {
                mgemm<false, 2, true, true><<<g24, blk, 0, stream>>>(
                    xmh, nullptr, 768, W1h + EXP_OFF, nullptr, nullptr, hmh, nullptr, G4,
                    b1 + G4, nullptr, nullptr, nullptr, nullptr, nullptr, nullptr, nullptr,
                    0, 0, 0, 0);
                mgemm<false, 0, true, false><<<g6z, blk, 0, stream>>>(
                    hmh, nullptr, G4, W2h + EXP_OFF, nullptr, eo, nullptr, nullptr, G4,
                    b2 + G4, nullptr, nullptr, nullptr, nullptr, nullptr, nullptr, nullptr,
                    768, (long)768 * 768, 768, 768);
                combine_k<false><<<ew, blk, 0, stream>>>(eo, wbuf, ibuf, hsumb, nullptr, nullptr);
            }
        }

        layernorm_k<<<Bc, blk, 0, stream>>>(hsumb, gamma, beta, outc);
    }
}